// Round 3
// baseline (195.403 us; speedup 1.0000x reference)
//
#include <hip/hip_runtime.h>
#include <hip/hip_bf16.h>

// Problem constants
#define CIN   256
#define COUT  128
#define BATCH 16
#define HH    32
#define WW    32
#define KD    2304      // 9 * 256, k = j*256 + c (j=0: silu, j=1..8: bases)
#define M_TOT 16384     // BATCH*HH*WW
#define N_TOT 512       // COUT*2*2

typedef __bf16 bf16x8 __attribute__((ext_vector_type(8)));
typedef float  f32x4  __attribute__((ext_vector_type(4)));

// ---- B-spline bases ----
// Knots g[i] = (i-3)*0.4 - 1, i=0..11 (uniform). Reference Cox-de-Boor over
// these 12 knots == cardinal cubic B-spline translates, truncated to j in [0,7].

// Slow/literal version (used only in tiny zbias kernel).
__device__ __forceinline__ void bases8_ref(float v, float* bb) {
    float g[12];
#pragma unroll
    for (int i = 0; i < 12; ++i) g[i] = (float)(i - 3) * 0.4f - 1.0f;
    float b[11];
#pragma unroll
    for (int j = 0; j < 11; ++j) b[j] = (v >= g[j] && v < g[j + 1]) ? 1.0f : 0.0f;
#pragma unroll
    for (int k = 1; k <= 3; ++k) {
#pragma unroll
        for (int j = 0; j + k < 11; ++j) {
            float left  = (v - g[j]) / (g[j + k] - g[j]) * b[j];
            float right = (g[j + k + 1] - v) / (g[j + k + 1] - g[j + 1]) * b[j + 1];
            b[j] = left + right;
        }
    }
#pragma unroll
    for (int j = 0; j < 8; ++j) bb[j] = b[j];
}

// Fast uniform-knot version: interval idx = floor(u), u = (v-g0)/h; the 4
// nonzero bases are the standard cubic blending weights; slot j gets
// B_{j-(idx-3)}(t), clipped to j in [0,7]. Outside [g0, g11): all zero.
__device__ __forceinline__ void bases8_fast(float v, float* bb) {
    float u = v * 2.5f + 5.5f;          // (v + 2.2) / 0.4
    bool inr = (u >= 0.0f) && (u < 11.0f);
    float fidx = floorf(u);
    int idx = (int)fidx;
    float t = u - fidx;
    float t2 = t * t, t3 = t2 * t;
    float omt = 1.0f - t;
    float B0 = omt * omt * omt * (1.0f / 6.0f);
    float B1 = (3.0f * t3 - 6.0f * t2 + 4.0f) * (1.0f / 6.0f);
    float B2 = (-3.0f * t3 + 3.0f * t2 + 3.0f * t + 1.0f) * (1.0f / 6.0f);
    float B3 = t3 * (1.0f / 6.0f);
#pragma unroll
    for (int j = 0; j < 8; ++j) {
        int r = j - idx + 3;            // which blending weight this slot holds
        float w = (r == 0) ? B0 : (r == 1) ? B1 : (r == 2) ? B2 : (r == 3) ? B3 : 0.0f;
        bb[j] = inr ? w : 0.0f;
    }
}

// Kernel 1: features. Block = one (b,h) strip (32 rows), thread = one channel c.
// A[row][j*256 + c], row = b*1024 + h*32 + w. Stores coalesced across c.
__global__ __launch_bounds__(256) void feat_kernel(const float* __restrict__ x,
                                                   __hip_bfloat16* __restrict__ A) {
    int bh = blockIdx.x;            // 0..511
    int b = bh >> 5, h = bh & 31;
    int c = threadIdx.x;            // 0..255
    const float* xp = x + (((size_t)(b * CIN + c) * HH + h) * WW);
    size_t rowbase = (size_t)bh * 32;
    for (int w = 0; w < WW; ++w) {
        float v = xp[w];
        float s = v / (1.0f + __expf(-v));   // silu
        float bb[8];
        bases8_fast(v, bb);
        __hip_bfloat16* ap = A + (rowbase + w) * KD + c;
        ap[0] = __float2bfloat16(s);
#pragma unroll
        for (int j = 0; j < 8; ++j) ap[(size_t)(j + 1) * 256] = __float2bfloat16(bb[j]);
    }
}

// Kernel 2: Z bias. Block = one o. a4[mn] = sum_{c,g} spline_w[o,c,m,n,g]*b0[g]
// (unflipped coords); Z[o][mn'] = tot - a4[3 - mn'] (kernel flip).
__global__ __launch_bounds__(256) void zbias_kernel(const float* __restrict__ sw,
                                                    float* __restrict__ Z) {
    int o = blockIdx.x;                 // 0..127
    int mn = threadIdx.x >> 6;          // 0..3 (storage order m*2+n)
    int lane = threadIdx.x & 63;
    float b0[8];
    bases8_ref(0.0f, b0);
    float p = 0.f;
    for (int cc = lane; cc < CIN; cc += 64) {
        const float* wp = sw + (((size_t)(o * CIN + cc) * 4 + mn) * 8);
#pragma unroll
        for (int gi = 0; gi < 8; ++gi) p += wp[gi] * b0[gi];
    }
#pragma unroll
    for (int off = 32; off; off >>= 1) p += __shfl_down(p, off);
    __shared__ float a4[4];
    if (lane == 0) a4[mn] = p;
    __syncthreads();
    if (threadIdx.x < 4) {
        float tot = a4[0] + a4[1] + a4[2] + a4[3];
        Z[o * 4 + (int)threadIdx.x] = tot - a4[3 - (int)threadIdx.x];
    }
}

// Kernel 3: weight repack -> Bm[n][k], n = o*4 + m2*2 + n2 (flipped taps), bf16.
__global__ __launch_bounds__(256) void repack_kernel(const float* __restrict__ bw,
                                                     const float* __restrict__ sw,
                                                     __hip_bfloat16* __restrict__ Bm) {
    int n = blockIdx.x;                 // 0..511
    int o = n >> 2, m2 = (n >> 1) & 1, n2 = n & 1;
    int mf = 1 - m2, nf = 1 - n2;
    for (int it = 0; it < 9; ++it) {
        int k = it * 256 + (int)threadIdx.x;
        int c = (int)threadIdx.x;
        float v;
        if (it == 0) v = bw[((size_t)(o * CIN + c) * 2 + mf) * 2 + nf];
        else         v = sw[(((size_t)(o * CIN + c) * 2 + mf) * 2 + nf) * 8 + (it - 1)];
        Bm[(size_t)n * KD + k] = __float2bfloat16(v);
    }
}

#define GLOBAL_AS __attribute__((address_space(1)))
#define LDS_AS    __attribute__((address_space(3)))
__device__ __forceinline__ void async_copy16(const void* g, void* l) {
    __builtin_amdgcn_global_load_lds((const GLOBAL_AS unsigned int*)g,
                                     (LDS_AS unsigned int*)l, 16, 0, 0);
}

// Kernel 4: GEMM. C[M=16384, N=512] = A[M,KD] * Bm[N,KD]^T + Z[n], scattered to out.
// 128x128 tile, BK=64, 4 waves (2x2), each wave 4x4 frags of 16x16x32 bf16 MFMA.
__global__ __launch_bounds__(256) void gemm_kernel(const __hip_bfloat16* __restrict__ A,
                                                   const __hip_bfloat16* __restrict__ Bm,
                                                   const float* __restrict__ Z,
                                                   float* __restrict__ out) {
    __shared__ __align__(16) __hip_bfloat16 As[128 * 64];
    __shared__ __align__(16) __hip_bfloat16 Bs[128 * 64];
    int tid = threadIdx.x;
    int mBase = blockIdx.x * 128;
    int nBase = blockIdx.y * 128;
    int wave = tid >> 6, lane = tid & 63;
    int wm = wave >> 1, wn = wave & 1;
    int lrow = lane & 15, ksel = lane >> 4;
    int row_a = tid >> 3, oct = tid & 7;

    f32x4 acc[4][4];
#pragma unroll
    for (int i = 0; i < 4; ++i)
#pragma unroll
        for (int j = 0; j < 4; ++j) acc[i][j] = (f32x4){0.f, 0.f, 0.f, 0.f};

    for (int kt = 0; kt < 36; ++kt) {
        int k0 = kt * 64;
        __syncthreads();   // previous tile consumed
#pragma unroll
        for (int call = 0; call < 4; ++call) {
            int row = call * 32 + row_a;
            const __hip_bfloat16* ga = A  + (size_t)(mBase + row) * KD + k0 + oct * 8;
            const __hip_bfloat16* gb = Bm + (size_t)(nBase + row) * KD + k0 + oct * 8;
            async_copy16(ga, &As[(call * 256 + tid) * 8]);
            async_copy16(gb, &Bs[(call * 256 + tid) * 8]);
        }
        __syncthreads();   // drains vmcnt(0): tile ready
#pragma unroll
        for (int ks = 0; ks < 2; ++ks) {
            bf16x8 af[4], bfr[4];
#pragma unroll
            for (int f = 0; f < 4; ++f) {
                af[f]  = *(const bf16x8*)&As[(wm * 64 + f * 16 + lrow) * 64 + ks * 32 + ksel * 8];
                bfr[f] = *(const bf16x8*)&Bs[(wn * 64 + f * 16 + lrow) * 64 + ks * 32 + ksel * 8];
            }
#pragma unroll
            for (int fm = 0; fm < 4; ++fm)
#pragma unroll
                for (int fn = 0; fn < 4; ++fn)
                    acc[fm][fn] = __builtin_amdgcn_mfma_f32_16x16x32_bf16(af[fm], bfr[fn], acc[fm][fn], 0, 0, 0);
        }
    }

    // Epilogue: C/D layout col = lane&15 (N), row = (lane>>4)*4 + reg (M) [m89].
#pragma unroll
    for (int fn = 0; fn < 4; ++fn) {
        int gn = nBase + wn * 64 + fn * 16 + lrow;
        float zv = Z[gn];
        int o = gn >> 2, m2 = (gn >> 1) & 1, n2 = gn & 1;
#pragma unroll
        for (int fm = 0; fm < 4; ++fm) {
#pragma unroll
            for (int r = 0; r < 4; ++r) {
                int gr = mBase + wm * 64 + fm * 16 + ksel * 4 + r;
                int b = gr >> 10, h = (gr >> 5) & 31, w = gr & 31;
                out[(((size_t)(b * COUT + o)) * 64 + (2 * h + m2)) * 64 + (2 * w + n2)] =
                    acc[fm][fn][r] + zv;
            }
        }
    }
}

extern "C" void kernel_launch(void* const* d_in, const int* in_sizes, int n_in,
                              void* d_out, int out_size, void* d_ws, size_t ws_size,
                              hipStream_t stream) {
    const float* x  = (const float*)d_in[0];
    const float* bw = (const float*)d_in[1];
    const float* sw = (const float*)d_in[2];
    float* out = (float*)d_out;

    __hip_bfloat16* Afeat = (__hip_bfloat16*)d_ws;                       // 16384*2304*2 B
    __hip_bfloat16* Bm    = Afeat + (size_t)M_TOT * KD;                  // 512*2304*2 B
    float*          Z     = (float*)(Bm + (size_t)N_TOT * KD);           // 512*4 B

    feat_kernel<<<dim3(512), dim3(256), 0, stream>>>(x, Afeat);
    zbias_kernel<<<dim3(128), dim3(256), 0, stream>>>(sw, Z);
    repack_kernel<<<dim3(512), dim3(256), 0, stream>>>(bw, sw, Bm);
    gemm_kernel<<<dim3(128, 4), dim3(256), 0, stream>>>(Afeat, Bm, Z, out);
}

// Round 4
// 177.202 us; speedup vs baseline: 1.1027x; 1.1027x over previous
//
#include <hip/hip_runtime.h>
#include <hip/hip_bf16.h>

// Problem constants
#define CIN   256
#define COUT  128
#define BATCH 16
#define HH    32
#define WW    32
#define KD    2304      // 9 * 256, k = j*256 + c (j=0: silu, j=1..8: bases)
#define M_TOT 16384     // BATCH*HH*WW
#define N_TOT 512       // COUT*2*2

typedef __bf16 bf16x8 __attribute__((ext_vector_type(8)));
typedef float  f32x4  __attribute__((ext_vector_type(4)));

// ---- B-spline bases ----
// Knots g[i] = (i-3)*0.4 - 1, i=0..11 (uniform).

// Literal Cox-de-Boor (tiny zbias path only).
__device__ __forceinline__ void bases8_ref(float v, float* bb) {
    float g[12];
#pragma unroll
    for (int i = 0; i < 12; ++i) g[i] = (float)(i - 3) * 0.4f - 1.0f;
    float b[11];
#pragma unroll
    for (int j = 0; j < 11; ++j) b[j] = (v >= g[j] && v < g[j + 1]) ? 1.0f : 0.0f;
#pragma unroll
    for (int k = 1; k <= 3; ++k) {
#pragma unroll
        for (int j = 0; j + k < 11; ++j) {
            float left  = (v - g[j]) / (g[j + k] - g[j]) * b[j];
            float right = (g[j + k + 1] - v) / (g[j + k + 1] - g[j + 1]) * b[j + 1];
            b[j] = left + right;
        }
    }
#pragma unroll
    for (int j = 0; j < 8; ++j) bb[j] = b[j];
}

// Fast uniform-knot version (verified vs ref in round 3, absmax 0.031).
__device__ __forceinline__ void bases8_fast(float v, float* bb) {
    float u = v * 2.5f + 5.5f;          // (v + 2.2) / 0.4
    bool inr = (u >= 0.0f) && (u < 11.0f);
    float fidx = floorf(u);
    int idx = (int)fidx;
    float t = u - fidx;
    float t2 = t * t, t3 = t2 * t;
    float omt = 1.0f - t;
    float B0 = omt * omt * omt * (1.0f / 6.0f);
    float B1 = (3.0f * t3 - 6.0f * t2 + 4.0f) * (1.0f / 6.0f);
    float B2 = (-3.0f * t3 + 3.0f * t2 + 3.0f * t + 1.0f) * (1.0f / 6.0f);
    float B3 = t3 * (1.0f / 6.0f);
#pragma unroll
    for (int j = 0; j < 8; ++j) {
        int r = j - idx + 3;
        float w = (r == 0) ? B0 : (r == 1) ? B1 : (r == 2) ? B2 : (r == 3) ? B3 : 0.0f;
        bb[j] = inr ? w : 0.0f;
    }
}

// Kernel 1: features, LDS-staged. Block = (b,h) strip; 4 chunks of 8 w.
// Phase A: thread c computes 9 features for 8 w, 2B lane-consecutive LDS writes.
// Phase B: bf16x8 (16B/lane) contiguous global stores of the whole chunk.
__global__ __launch_bounds__(256) void feat_kernel(const float* __restrict__ x,
                                                   __hip_bfloat16* __restrict__ A) {
    __shared__ __align__(16) __hip_bfloat16 lf[8 * KD];   // 36864 B
    int bh = blockIdx.x;            // 0..511
    int b = bh >> 5, h = bh & 31;
    int c = threadIdx.x;            // 0..255
    const float* xp = x + (((size_t)(b * CIN + c) * HH + h) * WW);
    size_t rowbase = (size_t)bh * 32;
    for (int chunk = 0; chunk < 4; ++chunk) {
        int w0 = chunk * 8;
        f32x4 xa = *(const f32x4*)(xp + w0);
        f32x4 xb = *(const f32x4*)(xp + w0 + 4);
        float xv[8] = {xa[0], xa[1], xa[2], xa[3], xb[0], xb[1], xb[2], xb[3]};
#pragma unroll
        for (int w = 0; w < 8; ++w) {
            float v = xv[w];
            float s = v / (1.0f + __expf(-v));   // silu
            float bb[8];
            bases8_fast(v, bb);
            lf[w * KD + c] = __float2bfloat16(s);
#pragma unroll
            for (int j = 0; j < 8; ++j)
                lf[w * KD + (j + 1) * 256 + c] = __float2bfloat16(bb[j]);
        }
        __syncthreads();
        // Flush: 2304 16B-units = 8 rows x 288 units; 9 stores/thread.
#pragma unroll
        for (int s = 0; s < 9; ++s) {
            int sid = s * 256 + (int)threadIdx.x;   // 0..2303
            int row = sid / 288;                     // 0..7
            int off = sid - row * 288;               // 0..287 (16B units)
            bf16x8 vv = *(const bf16x8*)&lf[row * KD + off * 8];
            *(bf16x8*)(A + (rowbase + w0 + row) * KD + off * 8) = vv;
        }
        __syncthreads();
    }
}

// Kernel 2 (fused): blocks 0..511 repack weights; 512..639 compute Z bias.
__global__ __launch_bounds__(256) void prep_kernel(const float* __restrict__ bw,
                                                   const float* __restrict__ sw,
                                                   __hip_bfloat16* __restrict__ Bm,
                                                   float* __restrict__ Z) {
    if (blockIdx.x < 512) {
        int n = blockIdx.x;                 // 0..511
        int o = n >> 2, m2 = (n >> 1) & 1, n2 = n & 1;
        int mf = 1 - m2, nf = 1 - n2;
#pragma unroll
        for (int it = 0; it < 9; ++it) {
            int k = it * 256 + (int)threadIdx.x;
            int c = (int)threadIdx.x;
            float v;
            if (it == 0) v = bw[((size_t)(o * CIN + c) * 2 + mf) * 2 + nf];
            else         v = sw[(((size_t)(o * CIN + c) * 2 + mf) * 2 + nf) * 8 + (it - 1)];
            Bm[(size_t)n * KD + k] = __float2bfloat16(v);
        }
    } else {
        int o = blockIdx.x - 512;           // 0..127
        int mn = threadIdx.x >> 6;          // 0..3 (storage order m*2+n)
        int lane = threadIdx.x & 63;
        float b0[8];
        bases8_ref(0.0f, b0);
        float p = 0.f;
        for (int cc = lane; cc < CIN; cc += 64) {
            const float* wp = sw + (((size_t)(o * CIN + cc) * 4 + mn) * 8);
#pragma unroll
            for (int gi = 0; gi < 8; ++gi) p += wp[gi] * b0[gi];
        }
#pragma unroll
        for (int off = 32; off; off >>= 1) p += __shfl_down(p, off);
        __shared__ float a4[4];
        if (lane == 0) a4[mn] = p;
        __syncthreads();
        if (threadIdx.x < 4) {
            float tot = a4[0] + a4[1] + a4[2] + a4[3];
            Z[o * 4 + (int)threadIdx.x] = tot - a4[3 - (int)threadIdx.x];
        }
    }
}

#define GLOBAL_AS __attribute__((address_space(1)))
#define LDS_AS    __attribute__((address_space(3)))
__device__ __forceinline__ void async_copy16(const void* g, void* l) {
    __builtin_amdgcn_global_load_lds((const GLOBAL_AS unsigned int*)g,
                                     (LDS_AS unsigned int*)l, 16, 0, 0);
}

// Kernel 3: GEMM with 2-phase dbuf prefetch + T2 XOR bank-swizzle.
// Swizzle (rule #21, both-sides): LDS dest linear (gload_lds constraint);
// SOURCE unit pre-swizzled oct^(row&7); reads XOR the same involution.
__global__ __launch_bounds__(256) void gemm_kernel(const __hip_bfloat16* __restrict__ A,
                                                   const __hip_bfloat16* __restrict__ Bm,
                                                   const float* __restrict__ Z,
                                                   float* __restrict__ out) {
    __shared__ __align__(16) __hip_bfloat16 As0[128 * 64], Bs0[128 * 64];
    __shared__ __align__(16) __hip_bfloat16 As1[128 * 64], Bs1[128 * 64];
    int tid = threadIdx.x;
    int mBase = blockIdx.x * 128;
    int nBase = blockIdx.y * 128;
    int wave = tid >> 6, lane = tid & 63;
    int wm = wave >> 1, wn = wave & 1;
    int lrow = lane & 15, ksel = lane >> 4;
    int row_a = tid >> 3, oct = tid & 7;
    int soct = oct ^ (row_a & 7);          // pre-swizzled source 16B-unit

    f32x4 acc[4][4];
#pragma unroll
    for (int i = 0; i < 4; ++i)
#pragma unroll
        for (int j = 0; j < 4; ++j) acc[i][j] = (f32x4){0.f, 0.f, 0.f, 0.f};

    auto stage = [&](int kt, __hip_bfloat16* as, __hip_bfloat16* bs) {
        int k0 = kt * 64;
#pragma unroll
        for (int call = 0; call < 4; ++call) {
            int row = call * 32 + row_a;
            const __hip_bfloat16* ga = A  + (size_t)(mBase + row) * KD + k0 + soct * 8;
            const __hip_bfloat16* gb = Bm + (size_t)(nBase + row) * KD + k0 + soct * 8;
            async_copy16(ga, as + (call * 256 + tid) * 8);
            async_copy16(gb, bs + (call * 256 + tid) * 8);
        }
    };
    auto compute = [&](const __hip_bfloat16* as, const __hip_bfloat16* bs) {
#pragma unroll
        for (int ks = 0; ks < 2; ++ks) {
            bf16x8 af[4], bfr[4];
#pragma unroll
            for (int f = 0; f < 4; ++f) {
                int ra = wm * 64 + f * 16 + lrow;
                int ua = (ks * 4 + ksel) ^ (ra & 7);
                af[f] = *(const bf16x8*)&as[ra * 64 + ua * 8];
                int rb = wn * 64 + f * 16 + lrow;
                int ub = (ks * 4 + ksel) ^ (rb & 7);
                bfr[f] = *(const bf16x8*)&bs[rb * 64 + ub * 8];
            }
#pragma unroll
            for (int fm = 0; fm < 4; ++fm)
#pragma unroll
                for (int fn = 0; fn < 4; ++fn)
                    acc[fm][fn] = __builtin_amdgcn_mfma_f32_16x16x32_bf16(af[fm], bfr[fn], acc[fm][fn], 0, 0, 0);
        }
    };

    stage(0, As0, Bs0);
    __syncthreads();                        // drains vmcnt(0): tile 0 ready
    for (int kt = 0; kt < 36; kt += 2) {
        stage(kt + 1, As1, Bs1);            // prefetch overlaps compute below
        compute(As0, Bs0);
        __syncthreads();                    // drain: tile kt+1 ready; buf0 free
        if (kt + 2 < 36) stage(kt + 2, As0, Bs0);
        compute(As1, Bs1);
        __syncthreads();
    }

    // Epilogue: C/D layout col = lane&15 (N), row = (lane>>4)*4 + reg (M) [m89].
#pragma unroll
    for (int fn = 0; fn < 4; ++fn) {
        int gn = nBase + wn * 64 + fn * 16 + lrow;
        float zv = Z[gn];
        int o = gn >> 2, m2 = (gn >> 1) & 1, n2 = gn & 1;
#pragma unroll
        for (int fm = 0; fm < 4; ++fm) {
#pragma unroll
            for (int r = 0; r < 4; ++r) {
                int gr = mBase + wm * 64 + fm * 16 + ksel * 4 + r;
                int b = gr >> 10, h = (gr >> 5) & 31, w = gr & 31;
                out[(((size_t)(b * COUT + o)) * 64 + (2 * h + m2)) * 64 + (2 * w + n2)] =
                    acc[fm][fn][r] + zv;
            }
        }
    }
}

extern "C" void kernel_launch(void* const* d_in, const int* in_sizes, int n_in,
                              void* d_out, int out_size, void* d_ws, size_t ws_size,
                              hipStream_t stream) {
    const float* x  = (const float*)d_in[0];
    const float* bw = (const float*)d_in[1];
    const float* sw = (const float*)d_in[2];
    float* out = (float*)d_out;

    __hip_bfloat16* Afeat = (__hip_bfloat16*)d_ws;                       // 16384*2304*2 B
    __hip_bfloat16* Bm    = Afeat + (size_t)M_TOT * KD;                  // 512*2304*2 B
    float*          Z     = (float*)(Bm + (size_t)N_TOT * KD);           // 512*4 B

    feat_kernel<<<dim3(512), dim3(256), 0, stream>>>(x, Afeat);
    prep_kernel<<<dim3(640), dim3(256), 0, stream>>>(bw, sw, Bm, Z);
    gemm_kernel<<<dim3(128, 4), dim3(256), 0, stream>>>(Afeat, Bm, Z, out);
}

// Round 5
// 162.212 us; speedup vs baseline: 1.2046x; 1.0924x over previous
//
#include <hip/hip_runtime.h>
#include <hip/hip_bf16.h>

// Problem constants
#define CIN   256
#define COUT  128
#define BATCH 16
#define HH    32
#define WW    32
#define KD    2304      // 9 * 256, k = j*256 + c (j=0: silu, j=1..8: bases)
#define M_TOT 16384     // BATCH*HH*WW
#define N_TOT 512       // COUT*2*2

typedef __bf16 bf16x8 __attribute__((ext_vector_type(8)));
typedef float  f32x4  __attribute__((ext_vector_type(4)));

// ---- B-spline bases ----
// Knots g[i] = (i-3)*0.4 - 1, i=0..11 (uniform).

// Literal Cox-de-Boor (tiny zbias path only).
__device__ __forceinline__ void bases8_ref(float v, float* bb) {
    float g[12];
#pragma unroll
    for (int i = 0; i < 12; ++i) g[i] = (float)(i - 3) * 0.4f - 1.0f;
    float b[11];
#pragma unroll
    for (int j = 0; j < 11; ++j) b[j] = (v >= g[j] && v < g[j + 1]) ? 1.0f : 0.0f;
#pragma unroll
    for (int k = 1; k <= 3; ++k) {
#pragma unroll
        for (int j = 0; j + k < 11; ++j) {
            float left  = (v - g[j]) / (g[j + k] - g[j]) * b[j];
            float right = (g[j + k + 1] - v) / (g[j + k + 1] - g[j + 1]) * b[j + 1];
            b[j] = left + right;
        }
    }
#pragma unroll
    for (int j = 0; j < 8; ++j) bb[j] = b[j];
}

// Fast uniform-knot version (verified vs ref: absmax 0.031 @ rounds 3-4).
__device__ __forceinline__ void bases8_fast(float v, float* bb) {
    float u = v * 2.5f + 5.5f;          // (v + 2.2) / 0.4
    bool inr = (u >= 0.0f) && (u < 11.0f);
    float fidx = floorf(u);
    int idx = (int)fidx;
    float t = u - fidx;
    float t2 = t * t, t3 = t2 * t;
    float omt = 1.0f - t;
    float B0 = omt * omt * omt * (1.0f / 6.0f);
    float B1 = (3.0f * t3 - 6.0f * t2 + 4.0f) * (1.0f / 6.0f);
    float B2 = (-3.0f * t3 + 3.0f * t2 + 3.0f * t + 1.0f) * (1.0f / 6.0f);
    float B3 = t3 * (1.0f / 6.0f);
#pragma unroll
    for (int j = 0; j < 8; ++j) {
        int r = j - idx + 3;
        float w = (r == 0) ? B0 : (r == 1) ? B1 : (r == 2) ? B2 : (r == 3) ? B3 : 0.0f;
        bb[j] = inr ? w : 0.0f;
    }
}

// Kernel 1 (v3): features with COALESCED x reads via LDS transpose.
// Block = (b, h, w-half): grid 1024 (4 blocks/CU, 16 waves/CU).
// Phase A: cooperative load x[b, 0:256, h, w0:w0+16] as 64B segments/row.
// Phase B: thread=c reads its column from LDS (pad 20 -> <=2-way banks),
//          computes 9 features, stores 2B/lane -> 128B/wave coalesced.
#define XS_LD 20
__global__ __launch_bounds__(256) void feat_kernel(const float* __restrict__ x,
                                                   __hip_bfloat16* __restrict__ A) {
    __shared__ __align__(16) float xs[256 * XS_LD];   // 20480 B
    int bh = blockIdx.x >> 1;       // 0..511
    int wh = blockIdx.x & 1;        // 0..1
    int b = bh >> 5, h = bh & 31;
    int t = threadIdx.x;
    int w0 = wh * 16;

    // Phase A: 4 passes; wave covers 16 rows x 64B.
    int ru = t >> 2, uu = t & 3;
#pragma unroll
    for (int pass = 0; pass < 4; ++pass) {
        int r = pass * 64 + ru;
        f32x4 v = *(const f32x4*)(x + (((size_t)(b * CIN + r) * HH + h) * WW) + w0 + uu * 4);
        *(f32x4*)&xs[r * XS_LD + uu * 4] = v;
    }
    __syncthreads();

    // Phase B: thread = channel c.
    int c = t;
    float xv[16];
#pragma unroll
    for (int k = 0; k < 4; ++k) {
        f32x4 v = *(const f32x4*)&xs[c * XS_LD + k * 4];
        xv[k * 4 + 0] = v[0]; xv[k * 4 + 1] = v[1];
        xv[k * 4 + 2] = v[2]; xv[k * 4 + 3] = v[3];
    }
    size_t rowbase = (size_t)bh * 32 + w0;
#pragma unroll
    for (int w = 0; w < 16; ++w) {
        float v = xv[w];
        float s = v / (1.0f + __expf(-v));   // silu
        float bb[8];
        bases8_fast(v, bb);
        __hip_bfloat16* ap = A + (rowbase + w) * KD + c;
        ap[0] = __float2bfloat16(s);
#pragma unroll
        for (int j = 0; j < 8; ++j) ap[(size_t)(j + 1) * 256] = __float2bfloat16(bb[j]);
    }
}

// Kernel 2 (v2): fused repack+zbias, one block per o (128 blocks).
// Coalesced float4 global reads -> padded LDS -> coalesced Bm writes + Z reduce.
#define PLD 257
__global__ __launch_bounds__(256) void prep_kernel(const float* __restrict__ bw,
                                                   const float* __restrict__ sw,
                                                   __hip_bfloat16* __restrict__ Bm,
                                                   float* __restrict__ Z) {
    __shared__ float ls[32 * PLD];   // [mn*8+g][c] unflipped, 32.9KB
    __shared__ float lb[4 * PLD];    // [mn][c]
    __shared__ float a4[4];
    int o = blockIdx.x;
    int t = threadIdx.x;

    // Load spline slice: 8192 floats = 2048 float4.
    const float* sp = sw + (size_t)o * (CIN * 4 * 8);
#pragma unroll
    for (int pass = 0; pass < 8; ++pass) {
        int q4 = pass * 256 + t;
        int f = q4 * 4;
        int c = f >> 5, rest = f & 31;
        int mn = rest >> 3, g0 = rest & 7;   // g0 in {0,4}
        f32x4 v = *(const f32x4*)(sp + f);
#pragma unroll
        for (int i = 0; i < 4; ++i) ls[(mn * 8 + g0 + i) * PLD + c] = v[i];
    }
    // Load base slice: 1024 floats = 256 float4; float4 covers mn 0..3 for c=t.
    {
        f32x4 v = *(const f32x4*)(bw + (size_t)o * (CIN * 4) + t * 4);
#pragma unroll
        for (int i = 0; i < 4; ++i) lb[i * PLD + t] = v[i];
    }
    __syncthreads();

    // Bm writes: n2loc = output tap (m2,n2); source = unflipped (3 - n2loc).
    int c = t;
#pragma unroll
    for (int n2loc = 0; n2loc < 4; ++n2loc) {
        int src = 3 - n2loc;
        __hip_bfloat16* bp = Bm + (size_t)(o * 4 + n2loc) * KD + c;
        bp[0] = __float2bfloat16(lb[src * PLD + c]);
#pragma unroll
        for (int it = 1; it < 9; ++it)
            bp[(size_t)it * 256] = __float2bfloat16(ls[(src * 8 + it - 1) * PLD + c]);
    }

    // Z: a4[mn] = sum_{c,g} ls[mn*8+g][c]*b0[g]; Z[o,mn'] = tot - a4[3-mn'].
    int mn = t >> 6, lane = t & 63;
    float b0[8];
    bases8_ref(0.0f, b0);
    float p = 0.f;
#pragma unroll
    for (int cc = 0; cc < 4; ++cc) {
        int ci = lane + cc * 64;
#pragma unroll
        for (int gi = 0; gi < 8; ++gi) p += ls[(mn * 8 + gi) * PLD + ci] * b0[gi];
    }
#pragma unroll
    for (int off = 32; off; off >>= 1) p += __shfl_down(p, off);
    if (lane == 0) a4[mn] = p;
    __syncthreads();
    if (t < 4) {
        float tot = a4[0] + a4[1] + a4[2] + a4[3];
        Z[o * 4 + t] = tot - a4[3 - t];
    }
}

#define GLOBAL_AS __attribute__((address_space(1)))
#define LDS_AS    __attribute__((address_space(3)))
__device__ __forceinline__ void async_copy16(const void* g, void* l) {
    __builtin_amdgcn_global_load_lds((const GLOBAL_AS unsigned int*)g,
                                     (LDS_AS unsigned int*)l, 16, 0, 0);
}

// Kernel 3: GEMM (unchanged from round 4): 2-phase dbuf + T2 XOR swizzle.
__global__ __launch_bounds__(256) void gemm_kernel(const __hip_bfloat16* __restrict__ A,
                                                   const __hip_bfloat16* __restrict__ Bm,
                                                   const float* __restrict__ Z,
                                                   float* __restrict__ out) {
    __shared__ __align__(16) __hip_bfloat16 As0[128 * 64], Bs0[128 * 64];
    __shared__ __align__(16) __hip_bfloat16 As1[128 * 64], Bs1[128 * 64];
    int tid = threadIdx.x;
    int mBase = blockIdx.x * 128;
    int nBase = blockIdx.y * 128;
    int wave = tid >> 6, lane = tid & 63;
    int wm = wave >> 1, wn = wave & 1;
    int lrow = lane & 15, ksel = lane >> 4;
    int row_a = tid >> 3, oct = tid & 7;
    int soct = oct ^ (row_a & 7);          // pre-swizzled source 16B-unit

    f32x4 acc[4][4];
#pragma unroll
    for (int i = 0; i < 4; ++i)
#pragma unroll
        for (int j = 0; j < 4; ++j) acc[i][j] = (f32x4){0.f, 0.f, 0.f, 0.f};

    auto stage = [&](int kt, __hip_bfloat16* as, __hip_bfloat16* bs) {
        int k0 = kt * 64;
#pragma unroll
        for (int call = 0; call < 4; ++call) {
            int row = call * 32 + row_a;
            const __hip_bfloat16* ga = A  + (size_t)(mBase + row) * KD + k0 + soct * 8;
            const __hip_bfloat16* gb = Bm + (size_t)(nBase + row) * KD + k0 + soct * 8;
            async_copy16(ga, as + (call * 256 + tid) * 8);
            async_copy16(gb, bs + (call * 256 + tid) * 8);
        }
    };
    auto compute = [&](const __hip_bfloat16* as, const __hip_bfloat16* bs) {
#pragma unroll
        for (int ks = 0; ks < 2; ++ks) {
            bf16x8 af[4], bfr[4];
#pragma unroll
            for (int f = 0; f < 4; ++f) {
                int ra = wm * 64 + f * 16 + lrow;
                int ua = (ks * 4 + ksel) ^ (ra & 7);
                af[f] = *(const bf16x8*)&as[ra * 64 + ua * 8];
                int rb = wn * 64 + f * 16 + lrow;
                int ub = (ks * 4 + ksel) ^ (rb & 7);
                bfr[f] = *(const bf16x8*)&bs[rb * 64 + ub * 8];
            }
#pragma unroll
            for (int fm = 0; fm < 4; ++fm)
#pragma unroll
                for (int fn = 0; fn < 4; ++fn)
                    acc[fm][fn] = __builtin_amdgcn_mfma_f32_16x16x32_bf16(af[fm], bfr[fn], acc[fm][fn], 0, 0, 0);
        }
    };

    stage(0, As0, Bs0);
    __syncthreads();
    for (int kt = 0; kt < 36; kt += 2) {
        stage(kt + 1, As1, Bs1);
        compute(As0, Bs0);
        __syncthreads();
        if (kt + 2 < 36) stage(kt + 2, As0, Bs0);
        compute(As1, Bs1);
        __syncthreads();
    }

    // Epilogue: C/D layout col = lane&15 (N), row = (lane>>4)*4 + reg (M) [m89].
#pragma unroll
    for (int fn = 0; fn < 4; ++fn) {
        int gn = nBase + wn * 64 + fn * 16 + lrow;
        float zv = Z[gn];
        int o = gn >> 2, m2 = (gn >> 1) & 1, n2 = gn & 1;
#pragma unroll
        for (int fm = 0; fm < 4; ++fm) {
#pragma unroll
            for (int r = 0; r < 4; ++r) {
                int gr = mBase + wm * 64 + fm * 16 + ksel * 4 + r;
                int b = gr >> 10, h = (gr >> 5) & 31, w = gr & 31;
                out[(((size_t)(b * COUT + o)) * 64 + (2 * h + m2)) * 64 + (2 * w + n2)] =
                    acc[fm][fn][r] + zv;
            }
        }
    }
}

extern "C" void kernel_launch(void* const* d_in, const int* in_sizes, int n_in,
                              void* d_out, int out_size, void* d_ws, size_t ws_size,
                              hipStream_t stream) {
    const float* x  = (const float*)d_in[0];
    const float* bw = (const float*)d_in[1];
    const float* sw = (const float*)d_in[2];
    float* out = (float*)d_out;

    __hip_bfloat16* Afeat = (__hip_bfloat16*)d_ws;                       // 16384*2304*2 B
    __hip_bfloat16* Bm    = Afeat + (size_t)M_TOT * KD;                  // 512*2304*2 B
    float*          Z     = (float*)(Bm + (size_t)N_TOT * KD);           // 512*4 B

    feat_kernel<<<dim3(1024), dim3(256), 0, stream>>>(x, Afeat);
    prep_kernel<<<dim3(128), dim3(256), 0, stream>>>(bw, sw, Bm, Z);
    gemm_kernel<<<dim3(128, 4), dim3(256), 0, stream>>>(Afeat, Bm, Z, out);
}

// Round 8
// 137.816 us; speedup vs baseline: 1.4179x; 1.1770x over previous
//
#include <hip/hip_runtime.h>
#include <hip/hip_bf16.h>

// Problem constants
#define CIN   256
#define COUT  128
#define BATCH 16
#define HH    32
#define WW    32
#define KD    2304      // 9 * 256, k = j*256 + c (j=0: silu, j=1..8: bases)
#define M_TOT 16384     // BATCH*HH*WW
#define N_TOT 512       // COUT*2*2

typedef __bf16 bf16x8 __attribute__((ext_vector_type(8)));
typedef float  f32x4  __attribute__((ext_vector_type(4)));

// ---- B-spline bases ----
// Knots g[i] = (i-3)*0.4 - 1, i=0..11 (uniform).

// Literal Cox-de-Boor (tiny zbias path only).
__device__ __forceinline__ void bases8_ref(float v, float* bb) {
    float g[12];
#pragma unroll
    for (int i = 0; i < 12; ++i) g[i] = (float)(i - 3) * 0.4f - 1.0f;
    float b[11];
#pragma unroll
    for (int j = 0; j < 11; ++j) b[j] = (v >= g[j] && v < g[j + 1]) ? 1.0f : 0.0f;
#pragma unroll
    for (int k = 1; k <= 3; ++k) {
#pragma unroll
        for (int j = 0; j + k < 11; ++j) {
            float left  = (v - g[j]) / (g[j + k] - g[j]) * b[j];
            float right = (g[j + k + 1] - v) / (g[j + k + 1] - g[j + 1]) * b[j + 1];
            b[j] = left + right;
        }
    }
#pragma unroll
    for (int j = 0; j < 8; ++j) bb[j] = b[j];
}

// Kernel 1 (v4): coalesced x reads (r5) + LDS feature tile with direct
// indexed scatter (replaces 8-slot select chain) + bf16x8 coalesced flush.
// Grid 1024 = (bh, w-half). Per block: xs[256][17] + lf[4][2304] = 35.8KB.
#define XS_LD 17
__global__ __launch_bounds__(256) void feat_kernel(const float* __restrict__ x,
                                                   __hip_bfloat16* __restrict__ A) {
    __shared__ __align__(16) float xs[256 * XS_LD];        // 17408 B
    __shared__ __align__(16) __hip_bfloat16 lf[4 * KD];    // 18432 B
    int bh = blockIdx.x >> 1;       // 0..511
    int wh = blockIdx.x & 1;        // 0..1
    int b = bh >> 5, h = bh & 31;
    int t = threadIdx.x;
    int w0 = wh * 16;

    // Phase A: coalesced x load; wave covers 16 rows x 64B.
    int ru = t >> 2, uu = t & 3;
#pragma unroll
    for (int pass = 0; pass < 4; ++pass) {
        int r = pass * 64 + ru;
        f32x4 v = *(const f32x4*)(x + (((size_t)(b * CIN + r) * HH + h) * WW) + w0 + uu * 4);
        *(f32x4*)&xs[r * XS_LD + uu * 4] = v;
    }
    __syncthreads();

    int c = t;
    size_t rowbase = (size_t)bh * 32 + w0;
    for (int chunk = 0; chunk < 4; ++chunk) {
        // Phase B: 4 w's -> lf. Scatter banks: bank = c>>1 (j*512B = bank-neutral),
        // 2 lanes/bank = free (m136).
#pragma unroll
        for (int wi = 0; wi < 4; ++wi) {
            float v = xs[c * XS_LD + chunk * 4 + wi];
            float s = v / (1.0f + __expf(-v));   // silu
            float u = v * 2.5f + 5.5f;           // (v + 2.2) / 0.4
            bool inr = (u >= 0.0f) && (u < 11.0f);
            float fidx = floorf(u);
            int idx = (int)fidx;
            float tt = u - fidx;
            float t2 = tt * tt, t3 = t2 * tt, omt = 1.0f - tt;
            float B0 = omt * omt * omt * (1.0f / 6.0f);
            float B1 = (3.0f * t3 - 6.0f * t2 + 4.0f) * (1.0f / 6.0f);
            float B2 = (-3.0f * t3 + 3.0f * t2 + 3.0f * tt + 1.0f) * (1.0f / 6.0f);
            float B3 = t3 * (1.0f / 6.0f);
            float Bv[4] = {B0, B1, B2, B3};
            __hip_bfloat16* lp = lf + wi * KD + c;
            lp[0] = __float2bfloat16(s);
#pragma unroll
            for (int j = 1; j <= 8; ++j) lp[j * 256] = __float2bfloat16(0.0f);
            if (inr) {
#pragma unroll
                for (int r_ = 0; r_ < 4; ++r_) {
                    int j = idx - 3 + r_;
                    if ((unsigned)j < 8u) lp[(j + 1) * 256] = __float2bfloat16(Bv[r_]);
                }
            }
        }
        __syncthreads();
        // Phase C: flush 4 rows x 288 16B-units, fully coalesced.
        for (int sid = t; sid < 1152; sid += 256) {
            int row = sid / 288, off = sid - row * 288;
            bf16x8 vv = *(const bf16x8*)&lf[row * KD + off * 8];
            *(bf16x8*)(A + (rowbase + chunk * 4 + row) * KD + off * 8) = vv;
        }
        __syncthreads();
    }
}

// Kernel 2: fused repack+zbias, one block per o (128 blocks).
#define PLD 257
__global__ __launch_bounds__(256) void prep_kernel(const float* __restrict__ bw,
                                                   const float* __restrict__ sw,
                                                   __hip_bfloat16* __restrict__ Bm,
                                                   float* __restrict__ Z) {
    __shared__ float ls[32 * PLD];   // [mn*8+g][c] unflipped
    __shared__ float lb[4 * PLD];    // [mn][c]
    __shared__ float a4[4];
    int o = blockIdx.x;
    int t = threadIdx.x;

    const float* sp = sw + (size_t)o * (CIN * 4 * 8);
#pragma unroll
    for (int pass = 0; pass < 8; ++pass) {
        int q4 = pass * 256 + t;
        int f = q4 * 4;
        int c = f >> 5, rest = f & 31;
        int mn = rest >> 3, g0 = rest & 7;   // g0 in {0,4}
        f32x4 v = *(const f32x4*)(sp + f);
#pragma unroll
        for (int i = 0; i < 4; ++i) ls[(mn * 8 + g0 + i) * PLD + c] = v[i];
    }
    {
        f32x4 v = *(const f32x4*)(bw + (size_t)o * (CIN * 4) + t * 4);
#pragma unroll
        for (int i = 0; i < 4; ++i) lb[i * PLD + t] = v[i];
    }
    __syncthreads();

    int c = t;
#pragma unroll
    for (int n2loc = 0; n2loc < 4; ++n2loc) {
        int src = 3 - n2loc;
        __hip_bfloat16* bp = Bm + (size_t)(o * 4 + n2loc) * KD + c;
        bp[0] = __float2bfloat16(lb[src * PLD + c]);
#pragma unroll
        for (int it = 1; it < 9; ++it)
            bp[(size_t)it * 256] = __float2bfloat16(ls[(src * 8 + it - 1) * PLD + c]);
    }

    int mn = t >> 6, lane = t & 63;
    float b0[8];
    bases8_ref(0.0f, b0);
    float p = 0.f;
#pragma unroll
    for (int cc = 0; cc < 4; ++cc) {
        int ci = lane + cc * 64;
#pragma unroll
        for (int gi = 0; gi < 8; ++gi) p += ls[(mn * 8 + gi) * PLD + ci] * b0[gi];
    }
#pragma unroll
    for (int off = 32; off; off >>= 1) p += __shfl_down(p, off);
    if (lane == 0) a4[mn] = p;
    __syncthreads();
    if (t < 4) {
        float tot = a4[0] + a4[1] + a4[2] + a4[3];
        Z[o * 4 + t] = tot - a4[3 - t];
    }
}

#define GLOBAL_AS __attribute__((address_space(1)))
#define LDS_AS    __attribute__((address_space(3)))
__device__ __forceinline__ void async_copy16(const void* g, void* l) {
    __builtin_amdgcn_global_load_lds((const GLOBAL_AS unsigned int*)g,
                                     (LDS_AS unsigned int*)l, 16, 0, 0);
}

// Kernel 3: GEMM: 2-phase dbuf + T2 XOR swizzle (r5, conflicts=0) + T5 setprio.
__global__ __launch_bounds__(256) void gemm_kernel(const __hip_bfloat16* __restrict__ A,
                                                   const __hip_bfloat16* __restrict__ Bm,
                                                   const float* __restrict__ Z,
                                                   float* __restrict__ out) {
    __shared__ __align__(16) __hip_bfloat16 As0[128 * 64], Bs0[128 * 64];
    __shared__ __align__(16) __hip_bfloat16 As1[128 * 64], Bs1[128 * 64];
    int tid = threadIdx.x;
    int mBase = blockIdx.x * 128;
    int nBase = blockIdx.y * 128;
    int wave = tid >> 6, lane = tid & 63;
    int wm = wave >> 1, wn = wave & 1;
    int lrow = lane & 15, ksel = lane >> 4;
    int row_a = tid >> 3, oct = tid & 7;
    int soct = oct ^ (row_a & 7);          // pre-swizzled source 16B-unit

    f32x4 acc[4][4];
#pragma unroll
    for (int i = 0; i < 4; ++i)
#pragma unroll
        for (int j = 0; j < 4; ++j) acc[i][j] = (f32x4){0.f, 0.f, 0.f, 0.f};

    auto stage = [&](int kt, __hip_bfloat16* as, __hip_bfloat16* bs) {
        int k0 = kt * 64;
#pragma unroll
        for (int call = 0; call < 4; ++call) {
            int row = call * 32 + row_a;
            const __hip_bfloat16* ga = A  + (size_t)(mBase + row) * KD + k0 + soct * 8;
            const __hip_bfloat16* gb = Bm + (size_t)(nBase + row) * KD + k0 + soct * 8;
            async_copy16(ga, as + (call * 256 + tid) * 8);
            async_copy16(gb, bs + (call * 256 + tid) * 8);
        }
    };
    auto compute = [&](const __hip_bfloat16* as, const __hip_bfloat16* bs) {
#pragma unroll
        for (int ks = 0; ks < 2; ++ks) {
            bf16x8 af[4], bfr[4];
#pragma unroll
            for (int f = 0; f < 4; ++f) {
                int ra = wm * 64 + f * 16 + lrow;
                int ua = (ks * 4 + ksel) ^ (ra & 7);
                af[f] = *(const bf16x8*)&as[ra * 64 + ua * 8];
                int rb = wn * 64 + f * 16 + lrow;
                int ub = (ks * 4 + ksel) ^ (rb & 7);
                bfr[f] = *(const bf16x8*)&bs[rb * 64 + ub * 8];
            }
            __builtin_amdgcn_s_setprio(1);
#pragma unroll
            for (int fm = 0; fm < 4; ++fm)
#pragma unroll
                for (int fn = 0; fn < 4; ++fn)
                    acc[fm][fn] = __builtin_amdgcn_mfma_f32_16x16x32_bf16(af[fm], bfr[fn], acc[fm][fn], 0, 0, 0);
            __builtin_amdgcn_s_setprio(0);
        }
    };

    stage(0, As0, Bs0);
    __syncthreads();
    for (int kt = 0; kt < 36; kt += 2) {
        stage(kt + 1, As1, Bs1);
        compute(As0, Bs0);
        __syncthreads();
        if (kt + 2 < 36) stage(kt + 2, As0, Bs0);
        compute(As1, Bs1);
        __syncthreads();
    }

    // Epilogue: C/D layout col = lane&15 (N), row = (lane>>4)*4 + reg (M) [m89].
#pragma unroll
    for (int fn = 0; fn < 4; ++fn) {
        int gn = nBase + wn * 64 + fn * 16 + lrow;
        float zv = Z[gn];
        int o = gn >> 2, m2 = (gn >> 1) & 1, n2 = gn & 1;
#pragma unroll
        for (int fm = 0; fm < 4; ++fm) {
#pragma unroll
            for (int r = 0; r < 4; ++r) {
                int gr = mBase + wm * 64 + fm * 16 + ksel * 4 + r;
                int b = gr >> 10, h = (gr >> 5) & 31, w = gr & 31;
                out[(((size_t)(b * COUT + o)) * 64 + (2 * h + m2)) * 64 + (2 * w + n2)] =
                    acc[fm][fn][r] + zv;
            }
        }
    }
}

extern "C" void kernel_launch(void* const* d_in, const int* in_sizes, int n_in,
                              void* d_out, int out_size, void* d_ws, size_t ws_size,
                              hipStream_t stream) {
    const float* x  = (const float*)d_in[0];
    const float* bw = (const float*)d_in[1];
    const float* sw = (const float*)d_in[2];
    float* out = (float*)d_out;

    __hip_bfloat16* Afeat = (__hip_bfloat16*)d_ws;                       // 16384*2304*2 B
    __hip_bfloat16* Bm    = Afeat + (size_t)M_TOT * KD;                  // 512*2304*2 B
    float*          Z     = (float*)(Bm + (size_t)N_TOT * KD);           // 512*4 B

    feat_kernel<<<dim3(1024), dim3(256), 0, stream>>>(x, Afeat);
    prep_kernel<<<dim3(128), dim3(256), 0, stream>>>(bw, sw, Bm, Z);
    gemm_kernel<<<dim3(128, 4), dim3(256), 0, stream>>>(Afeat, Bm, Z, out);
}